// Round 11
// baseline (1404.083 us; speedup 1.0000x reference)
//
#include <hip/hip_runtime.h>
#include <hip/hip_bf16.h>
#include <math.h>

typedef float f32x4 __attribute__((ext_vector_type(4)));
typedef __bf16 bf16x4 __attribute__((ext_vector_type(4)));
typedef __bf16 bf16x8 __attribute__((ext_vector_type(8)));

#define AS1(p) ((const __attribute__((address_space(1))) void*)(p))
#define AS3(p) ((__attribute__((address_space(3))) void*)(p))

static constexpr int D_MODEL = 1024;
static constexpr int S_LEN   = 2048;
static constexpr int BATCH   = 4;
static constexpr int NTOK    = BATCH * S_LEN;   // 8192
static constexpr int NH      = 8;
static constexpr int DH      = 32;
static constexpr int NA      = NH * DH * DH;    // 8192
static constexpr int D_FF    = 4096;
static constexpr int CHUNK   = 16;
static constexpr int NCHUNK  = S_LEN / CHUNK;   // 128

// GROUP_M=8 XCD-aware swizzle (requires gridDim.y % 8 == 0).
__device__ __forceinline__ void xcd_swizzle(int& bx, int& by) {
  int gx = gridDim.x;
  int orig = by * gx + bx;
  int r8 = orig & 7, j = orig >> 3;
  int bxn = j % gx, grp = j / gx;
  bx = bxn;
  by = grp * 8 + r8;
}

// Exact-GELU via A&S 7.1.26 erf approx (|eps| <= 1.5e-7 abs).
__device__ __forceinline__ float gelu_erf_fast(float v) {
  float z = fabsf(v) * 0.70710678118654752f;
  float t = __builtin_amdgcn_rcpf(fmaf(0.3275911f, z, 1.0f));
  float p = t * (0.254829592f + t * (-0.284496736f + t * (1.421413741f +
            t * (-1.453152027f + t * 1.061405429f))));
  float e = __builtin_amdgcn_exp2f(-1.4426950408889634f * z * z);
  float er = 1.0f - p * e;
  er = (v < 0.0f) ? -er : er;
  return 0.5f * v * (1.0f + er);
}

// ---------------------------------------------------------------------------
// Transpose fp32 [R][C] -> bf16 [C][R]
// ---------------------------------------------------------------------------
__global__ __launch_bounds__(256) void transpose_bf16(
    const float* __restrict__ in, __bf16* __restrict__ out, int R, int C) {
  __shared__ float tile[32][33];
  int tx = threadIdx.x & 31, ty = threadIdx.x >> 5;   // 32 x 8
  int c0 = blockIdx.x * 32, r0 = blockIdx.y * 32;
  for (int i = ty; i < 32; i += 8)
    tile[i][tx] = in[(size_t)(r0 + i) * C + c0 + tx];
  __syncthreads();
  for (int i = ty; i < 32; i += 8)
    out[(size_t)(c0 + i) * R + r0 + tx] = (__bf16)tile[tx][i];
}

// ---------------------------------------------------------------------------
// Transpose fp32 [R][C] -> SPLIT bf16 hi/lo [C][R]  (x = hi + lo)
// ---------------------------------------------------------------------------
__global__ __launch_bounds__(256) void transpose_split(
    const float* __restrict__ in, __bf16* __restrict__ ohi,
    __bf16* __restrict__ olo, int R, int C) {
  __shared__ float tile[32][33];
  int tx = threadIdx.x & 31, ty = threadIdx.x >> 5;
  int c0 = blockIdx.x * 32, r0 = blockIdx.y * 32;
  for (int i = ty; i < 32; i += 8)
    tile[i][tx] = in[(size_t)(r0 + i) * C + c0 + tx];
  __syncthreads();
  for (int i = ty; i < 32; i += 8) {
    float v = tile[tx][i];
    __bf16 h = (__bf16)v;
    ohi[(size_t)(c0 + i) * R + r0 + tx] = h;
    olo[(size_t)(c0 + i) * R + r0 + tx] = (__bf16)(v - (float)h);
  }
}

// ---------------------------------------------------------------------------
// LayerNorm: fp32 in. MODE=1 -> fp32; =0 -> bf16; =2 -> split hi/lo bf16
// ---------------------------------------------------------------------------
template <int MODE>
__global__ __launch_bounds__(256) void ln_kernel(
    const float* __restrict__ in, const float* __restrict__ g,
    const float* __restrict__ bta, void* __restrict__ outv,
    void* __restrict__ outv2) {
  int row = blockIdx.x, tid = threadIdx.x;
  const float4* in4 = (const float4*)(in + (size_t)row * D_MODEL);
  float4 v = in4[tid];
  float s  = v.x + v.y + v.z + v.w;
  float ss = v.x * v.x + v.y * v.y + v.z * v.z + v.w * v.w;
  for (int o = 32; o; o >>= 1) { s += __shfl_down(s, o); ss += __shfl_down(ss, o); }
  __shared__ float ps[4], pq[4];
  int lane = tid & 63, w = tid >> 6;
  if (lane == 0) { ps[w] = s; pq[w] = ss; }
  __syncthreads();
  s  = ps[0] + ps[1] + ps[2] + ps[3];
  ss = pq[0] + pq[1] + pq[2] + pq[3];
  float mean = s * (1.0f / D_MODEL);
  float var  = ss * (1.0f / D_MODEL) - mean * mean;
  float inv  = rsqrtf(fmaxf(var, 0.0f) + 1e-5f);
  float4 gv = ((const float4*)g)[tid];
  float4 bv = ((const float4*)bta)[tid];
  float o0 = (v.x - mean) * inv * gv.x + bv.x;
  float o1 = (v.y - mean) * inv * gv.y + bv.y;
  float o2 = (v.z - mean) * inv * gv.z + bv.z;
  float o3 = (v.w - mean) * inv * gv.w + bv.w;
  if (MODE == 1) {
    float4 o = {o0, o1, o2, o3};
    ((float4*)outv)[(size_t)row * (D_MODEL / 4) + tid] = o;
  } else if (MODE == 0) {
    bf16x4 o;
    o[0] = (__bf16)o0; o[1] = (__bf16)o1; o[2] = (__bf16)o2; o[3] = (__bf16)o3;
    ((bf16x4*)outv)[(size_t)row * (D_MODEL / 4) + tid] = o;
  } else {
    bf16x4 oh, ol;
    oh[0] = (__bf16)o0; oh[1] = (__bf16)o1; oh[2] = (__bf16)o2; oh[3] = (__bf16)o3;
    ol[0] = (__bf16)(o0 - (float)oh[0]);
    ol[1] = (__bf16)(o1 - (float)oh[1]);
    ol[2] = (__bf16)(o2 - (float)oh[2]);
    ol[3] = (__bf16)(o3 - (float)oh[3]);
    ((bf16x4*)outv )[(size_t)row * (D_MODEL / 4) + tid] = oh;
    ((bf16x4*)outv2)[(size_t)row * (D_MODEL / 4) + tid] = ol;
  }
}

enum { EPI_BF16_BIAS = 0, EPI_BF16_BIAS_GELU = 1, EPI_F32_BIAS_RES = 2,
       EPI_F32_BIAS_ONLY = 3, EPI_F32_ATOMIC = 4 };

#define SB0() __builtin_amdgcn_sched_barrier(0)
#define BARRIER()                                      \
  do {                                                 \
    SB0();                                             \
    __builtin_amdgcn_s_barrier();                      \
    SB0();                                             \
  } while (0)
#define LGKM0()                                        \
  do {                                                 \
    asm volatile("s_waitcnt lgkmcnt(0)" ::: "memory"); \
    SB0();                                             \
  } while (0)
#define GEMM8_QUAD(I0, J0)                                                   \
  do {                                                                       \
    __builtin_amdgcn_s_setprio(1);                                           \
    _Pragma("unroll") for (int i_ = 0; i_ < 4; ++i_)                         \
    _Pragma("unroll") for (int j_ = 0; j_ < 2; ++j_)                         \
    _Pragma("unroll") for (int k_ = 0; k_ < 2; ++k_)                         \
      acc[(I0) + i_][(J0) + j_] = __builtin_amdgcn_mfma_f32_16x16x32_bf16(   \
          a[(I0) + i_][k_], b[(J0) + j_][k_], acc[(I0) + i_][(J0) + j_],     \
          0, 0, 0);                                                          \
    __builtin_amdgcn_s_setprio(0);                                           \
  } while (0)

// ---------------------------------------------------------------------------
// 8-wave 256x256 MFMA GEMM, software-pipelined phases (bench-verified r6-r10).
// SPLIT=1: virtual K=3072 over (Ahi*Bhi + Ahi*Blo + Alo*Bhi), Kstride=1024.
// SPLITK=1: gridDim.z K-halves, per-half K cols at row stride `kstride`;
//   EPI_F32_ATOMIC accumulates into out (which pre-holds the residual base);
//   b2 folded into the z==0 half's bias -> no pre-pass, no write-write race.
// Live regs: acc(128) + a[8][2](64) + b[4][2](32) — no spill.
// ---------------------------------------------------------------------------
template <int SPLIT, int SPLITK, int EPI>
__global__ __launch_bounds__(512, 2) void gemm8(
    const __bf16* __restrict__ pA, const __bf16* __restrict__ pA2,
    const __bf16* __restrict__ pB, const __bf16* __restrict__ pB2,
    const float* __restrict__ bias, void* __restrict__ out,
    int M, int N, int K, int kstride) {
  __shared__ alignas(16) char lds[131072];   // A: [0,64K) 2 bufs; B: [64K,128K)
  const int tid = threadIdx.x;
  const int lane = tid & 63, w = tid >> 6;
  const int fm = lane & 15, fq = lane >> 4;
  const int wm2 = w >> 2, wn4 = w & 3;
  int bx = blockIdx.x, by = blockIdx.y;
  xcd_swizzle(bx, by);
  const int m0 = by * 256, n0 = bx * 256;
  const int NT = SPLIT ? 48 : (K >> 6);
  const int KS = SPLIT ? D_MODEL : kstride;

  // split-K column offset (element units within each row)
  const size_t kzoff = SPLITK ? (size_t)blockIdx.z * (size_t)K : 0;
  const __bf16* pAz = pA + kzoff;
  const __bf16* pBz = pB + kzoff;

  const int lrow8 = lane >> 3;                   // 0..7 (row within 8-row span)
  const int lslot = ((lane & 7) ^ lrow8) << 3;   // inverse-swizzled src slot

  auto stageA = [&](int kt, int h) {   // one half = 128 rows, 2 gload_lds/wave
    const __bf16* base = SPLIT ? ((kt < 32) ? pA : pA2) : pAz;
    int kc = SPLIT ? ((kt & 15) << 6) : (kt << 6);
    char* d0 = lds + ((kt & 1) << 15);
#pragma unroll
    for (int j = 0; j < 2; ++j) {
      int rb = h * 128 + j * 64 + w * 8;
      const __bf16* src = base + (size_t)(m0 + rb + lrow8) * KS + kc + lslot;
      __builtin_amdgcn_global_load_lds(AS1(src), AS3(d0 + rb * 128 + lane * 16), 16, 0, 0);
    }
  };
  auto stageB = [&](int kt, int h) {
    const __bf16* base = SPLIT ? ((kt >= 16 && kt < 32) ? pB2 : pB) : pBz;
    int kc = SPLIT ? ((kt & 15) << 6) : (kt << 6);
    char* d0 = lds + 65536 + ((kt & 1) << 15);
#pragma unroll
    for (int j = 0; j < 2; ++j) {
      int rb = h * 128 + j * 64 + w * 8;
      const __bf16* src = base + (size_t)(n0 + rb + lrow8) * KS + kc + lslot;
      __builtin_amdgcn_global_load_lds(AS1(src), AS3(d0 + rb * 128 + lane * 16), 16, 0, 0);
    }
  };
  auto rdA = [&](int bo, int i, int ks) -> bf16x8 {
    int row = wm2 * 128 + i * 16 + fm;
    return *(const bf16x8*)(lds + bo + row * 128 +
                            ((((ks << 2) + fq) ^ (row & 7)) << 4));
  };
  auto rdB = [&](int bo, int j, int ks) -> bf16x8 {
    int row = wn4 * 64 + j * 16 + fm;
    return *(const bf16x8*)(lds + 65536 + bo + row * 128 +
                            ((((ks << 2) + fq) ^ (row & 7)) << 4));
  };

  f32x4 acc[8][4];
#pragma unroll
  for (int i = 0; i < 8; ++i)
#pragma unroll
    for (int j = 0; j < 4; ++j)
#pragma unroll
      for (int r = 0; r < 4; ++r) acc[i][j][r] = 0.0f;

  // Prologue: tile0 fully + A0h(1) in flight; pre-read a0-3,b0-1 of tile0.
  stageA(0, 0); stageA(0, 1); stageB(0, 0); stageB(0, 1);
  if (NT > 1) stageA(1, 0);
  SB0();
  if (NT > 1) asm volatile("s_waitcnt vmcnt(2)" ::: "memory");
  else        asm volatile("s_waitcnt vmcnt(0)" ::: "memory");
  BARRIER();
  bf16x8 a[8][2], b[4][2];
#pragma unroll
  for (int i = 0; i < 4; ++i) { a[i][0] = rdA(0, i, 0); a[i][1] = rdA(0, i, 1); }
#pragma unroll
  for (int j = 0; j < 2; ++j) { b[j][0] = rdB(0, j, 0); b[j][1] = rdB(0, j, 1); }

  for (int t = 0; t < NT; ++t) {
    const int bo  = (t & 1) << 15;
    const int bon = ((t + 1) & 1) << 15;
    // ---- ph0
    BARRIER();
    if (t + 1 < NT) { stageA(t + 1, 1); stageB(t + 1, 0); }
    LGKM0();
#pragma unroll
    for (int j = 2; j < 4; ++j) { b[j][0] = rdB(bo, j, 0); b[j][1] = rdB(bo, j, 1); }
    SB0();
    GEMM8_QUAD(0, 0);
    // ---- ph1
    BARRIER();
    if (t + 1 < NT) stageB(t + 1, 1);
    LGKM0();
#pragma unroll
    for (int i = 4; i < 8; ++i) { a[i][0] = rdA(bo, i, 0); a[i][1] = rdA(bo, i, 1); }
    SB0();
    GEMM8_QUAD(0, 2);
    // ---- ph2
    BARRIER();
    LGKM0();
    GEMM8_QUAD(4, 0);
    // ---- ph3
    BARRIER();
    if (t + 2 < NT) stageA(t + 2, 0);
    SB0();
    if (t + 1 < NT) {
      if (t + 2 < NT) asm volatile("s_waitcnt vmcnt(2)" ::: "memory");
      else            asm volatile("s_waitcnt vmcnt(0)" ::: "memory");
      BARRIER();
#pragma unroll
      for (int i = 0; i < 4; ++i) { a[i][0] = rdA(bon, i, 0); a[i][1] = rdA(bon, i, 1); }
#pragma unroll
      for (int j = 0; j < 2; ++j) { b[j][0] = rdB(bon, j, 0); b[j][1] = rdB(bon, j, 1); }
      SB0();
    }
    GEMM8_QUAD(4, 2);
  }
  __syncthreads();

  if (EPI == EPI_F32_BIAS_ONLY) {
    float* outF = (float*)out;
#pragma unroll
    for (int j = 0; j < 4; ++j) {
      int col = n0 + wn4 * 64 + j * 16 + fm;
      float bv = bias[col];
#pragma unroll
      for (int i = 0; i < 8; ++i)
#pragma unroll
        for (int r = 0; r < 4; ++r) {
          int row = m0 + wm2 * 128 + i * 16 + fq * 4 + r;
          outF[(size_t)row * N + col] = acc[i][j][r] + bv;
        }
    }
  } else if (EPI == EPI_F32_ATOMIC) {
    // out pre-holds the residual base (x2); both K-halves atomicAdd partials;
    // z==0 also adds the bias. No ordering required (all adds commutative).
    float* outF = (float*)out;
#pragma unroll
    for (int j = 0; j < 4; ++j) {
      int col = n0 + wn4 * 64 + j * 16 + fm;
      float bv = (blockIdx.z == 0) ? bias[col] : 0.0f;
#pragma unroll
      for (int i = 0; i < 8; ++i)
#pragma unroll
        for (int r = 0; r < 4; ++r) {
          int row = m0 + wm2 * 128 + i * 16 + fq * 4 + r;
          atomicAdd(&outF[(size_t)row * N + col], acc[i][j][r] + bv);
        }
    }
  } else {  // EPI_BF16_BIAS_GELU: per-wave LDS bounce -> coalesced bf16x8
    char* patch = lds + w * 16384;
    float bv4[4];
#pragma unroll
    for (int j = 0; j < 4; ++j) bv4[j] = bias[n0 + wn4 * 64 + j * 16 + fm];
#pragma unroll
    for (int i = 0; i < 8; ++i)
#pragma unroll
      for (int j = 0; j < 4; ++j)
#pragma unroll
        for (int r = 0; r < 4; ++r) {
          float v = gelu_erf_fast(acc[i][j][r] + bv4[j]);
          *(__bf16*)(patch + (i * 16 + fq * 4 + r) * 128 + (j * 16 + fm) * 2) =
              (__bf16)v;
        }
    asm volatile("s_waitcnt lgkmcnt(0)" ::: "memory");
#pragma unroll
    for (int rr = 0; rr < 16; ++rr) {
      bf16x8 ov = *(const bf16x8*)(patch + (rr * 8 + lrow8) * 128 + (lane & 7) * 16);
      size_t grow = (size_t)(m0 + wm2 * 128 + rr * 8 + lrow8);
      *(bf16x8*)((__bf16*)out + grow * N + n0 + wn4 * 64 + (lane & 7) * 8) = ov;
    }
  }
}

// ---------------------------------------------------------------------------
// bf16 MFMA GEMM, m97 structure + GROUP_M=8 XCD swizzle (step 4 only now).
// (256,3): ask for 3 waves/SIMD — compiler shaves ~8 regs vs the 176-unified
// 2-wave default. Spill would show as WRITE_SIZE blowup on step 4.
// ---------------------------------------------------------------------------
template <int EPI>
__global__ __launch_bounds__(256, 3) void gemm_bf16(
    const __bf16* __restrict__ Amat, const __bf16* __restrict__ BT,
    const float* __restrict__ bias, const float* __restrict__ res,
    void* __restrict__ out, int M, int N, int K) {
  __shared__ __bf16 smem[2 * 128 * 32];        // As | Bs (contiguous 16KB)
  __bf16* As = smem;
  __bf16* Bs = smem + 128 * 32;
  const int tid = threadIdx.x;
  const int lane = tid & 63, w = tid >> 6;
  int bx = blockIdx.x, by = blockIdx.y;
  xcd_swizzle(bx, by);
  const int m0 = by * 128, n0 = bx * 128;
  const int wm = (w >> 1) * 64, wn = (w & 1) * 64;

  f32x4 acc[4][4];
#pragma unroll
  for (int a = 0; a < 4; a++)
#pragma unroll
    for (int b = 0; b < 4; b++)
#pragma unroll
      for (int r = 0; r < 4; r++) acc[a][b][r] = 0.0f;

  const int srow = tid >> 2;
  const int soff = (tid & 3) * 16;
  const __bf16* gA0 = Amat + (size_t)(m0 + srow) * K + (soff >> 1);
  const __bf16* gA1 = Amat + (size_t)(m0 + srow + 64) * K + (soff >> 1);
  const __bf16* gB0 = BT + (size_t)(n0 + srow) * K + (soff >> 1);
  const __bf16* gB1 = BT + (size_t)(n0 + srow + 64) * K + (soff >> 1);
  char* lA0 = (char*)As + srow * 64 + soff;
  char* lA1 = (char*)As + (srow + 64) * 64 + soff;
  char* lB0 = (char*)Bs + srow * 64 + soff;
  char* lB1 = (char*)Bs + (srow + 64) * 64 + soff;

  const int fm = lane & 15, fq = lane >> 4;
  for (int k0 = 0; k0 < K; k0 += 32) {
    __builtin_amdgcn_global_load_lds(AS1(gA0 + k0), AS3(lA0), 16, 0, 0);
    __builtin_amdgcn_global_load_lds(AS1(gA1 + k0), AS3(lA1), 16, 0, 0);
    __builtin_amdgcn_global_load_lds(AS1(gB0 + k0), AS3(lB0), 16, 0, 0);
    __builtin_amdgcn_global_load_lds(AS1(gB1 + k0), AS3(lB1), 16, 0, 0);
    __syncthreads();
    bf16x8 af[4], bf[4];
#pragma unroll
    for (int t = 0; t < 4; t++)
      af[t] = *(const bf16x8*)((const char*)As + (wm + t * 16 + fm) * 64 + fq * 16);
#pragma unroll
    for (int t = 0; t < 4; t++)
      bf[t] = *(const bf16x8*)((const char*)Bs + (wn + t * 16 + fm) * 64 + fq * 16);
#pragma unroll
    for (int tm = 0; tm < 4; tm++)
#pragma unroll
      for (int tn = 0; tn < 4; tn++)
        acc[tm][tn] = __builtin_amdgcn_mfma_f32_16x16x32_bf16(af[tm], bf[tn], acc[tm][tn], 0, 0, 0);
    __syncthreads();
  }

#pragma unroll
  for (int tn = 0; tn < 4; tn++) {
    int col = n0 + wn + tn * 16 + fm;
    float bv = bias[col];
#pragma unroll
    for (int tm = 0; tm < 4; tm++) {
#pragma unroll
      for (int r = 0; r < 4; r++) {
        int row = m0 + wm + tm * 16 + fq * 4 + r;
        float v = acc[tm][tn][r] + bv;
        size_t idx = (size_t)row * N + col;
        if (EPI == EPI_F32_BIAS_RES) {
          ((float*)out)[idx] = v + res[idx];
        } else if (EPI == EPI_BF16_BIAS_GELU) {
          v = gelu_erf_fast(v);
          ((__bf16*)out)[idx] = (__bf16)v;
        } else {
          ((__bf16*)out)[idx] = (__bf16)v;
        }
      }
    }
  }
}

// ---------------------------------------------------------------------------
// Phase 1 (per batch b): prefix products, IN PLACE over A.
// ---------------------------------------------------------------------------
__global__ __launch_bounds__(64) void mps_chunkprod_f32(
    float* __restrict__ A) {
  int bid = blockIdx.x;            // hh*128 + c
  int c = bid & 127, hh = bid >> 7;
  int lane = threadIdx.x;
  int jj = lane & 31, half = lane >> 5;
  __shared__ float Albuf[2][DH * DH];   // 2 x 4 KB

  float curc[32];
#pragma unroll
  for (int k = 0; k < 32; k++) curc[k] = (k == jj) ? 1.0f : 0.0f;

  float* Abase = A + (size_t)(c * CHUNK) * NA + (size_t)hh * (DH * DH);

  {  // stage t=0
    const float4* src = (const float4*)Abase;
    float4* dst = (float4*)Albuf[0];
#pragma unroll
    for (int r = 0; r < 4; r++) dst[lane + 64 * r] = src[lane + 64 * r];
  }
  __syncthreads();

  for (int t = 0; t < CHUNK; t++) {
    int cb = t & 1;
    float4 pf[4];
    if (t + 1 < CHUNK) {
      const float4* srcn = (const float4*)(Abase + (size_t)(t + 1) * NA);
#pragma unroll
      for (int r = 0; r < 4; r++) pf[r] = srcn[lane + 64 * r];
    }
    float nxt[16];
#pragma unroll
    for (int i16 = 0; i16 < 16; i16++) {
      const float4* ap = (const float4*)&Albuf[cb][(half * 16 + i16) * 32];
      float a0 = 0.f, a1 = 0.f, a2 = 0.f, a3 = 0.f;
#pragma unroll
      for (int k4 = 0; k4 < 8; k4++) {
        float4 av = ap[k4];
        a0 += av.x * curc[k4 * 4 + 0];
        a1 += av.y * curc[k4 * 4 + 1];
        a2 += av.z * curc[k4 * 4 + 2];
        a3 += av.w * curc[k4 * 4 + 3];
      }
      nxt[i16] = (a0 + a1) + (a2 + a3);
    }
    {
      float* slot = Abase + (size_t)t * NA;
#pragma unroll
      for (int i16 = 0; i16 < 16; i16++)
        slot[(half * 16 + i16) * 32 + jj] = nxt[i16];
    }
#pragma unroll
    for (int i16 = 0; i16 < 16; i16++) {
      float mine  = nxt[i16];
      float other = __shfl_xor(mine, 32);
      curc[i16]      = (half == 0) ? mine  : other;
      curc[16 + i16] = (half == 0) ? other : mine;
    }
    if (t + 1 < CHUNK) {
      float4* dst = (float4*)Albuf[cb ^ 1];
#pragma unroll
      for (int r = 0; r < 4; r++) dst[lane + 64 * r] = pf[r];
      __syncthreads();
    }
  }
}

// ---------------------------------------------------------------------------
// Phase 2 (per batch b): sequential scan over chunk products per head.
// Depth-4 register prefetch (named regs, static indices — rule #20).
// ---------------------------------------------------------------------------
__global__ __launch_bounds__(64) void mps_chunkscan(
    const float* __restrict__ pref, const float* __restrict__ h0,
    float* __restrict__ hstart) {
  int hh = blockIdx.x;
  int lane = threadIdx.x, i = lane & 31, half = lane >> 5;
  float hv = h0[hh * 32 + i];
  const size_t cstride = (size_t)CHUNK * NA;
  const float* row = pref + (size_t)(CHUNK - 1) * NA + (size_t)hh * (DH * DH)
                     + i * 32 + half * 16;
  int kb = half * 16;

  float4 pf0[4], pf1[4], pf2[4], pf3[4];
#pragma unroll
  for (int r = 0; r < 4; r++) pf0[r] = ((const float4*)row)[r];
#pragma unroll
  for (int r = 0; r < 4; r++) pf1[r] = ((const float4*)(row + cstride))[r];
#pragma unroll
  for (int r = 0; r < 4; r++) pf2[r] = ((const float4*)(row + 2 * cstride))[r];
#pragma unroll
  for (int r = 0; r < 4; r++) pf3[r] = ((const float4*)(row + 3 * cstride))[r];

  for (int c = 0; c < NCHUNK; c++) {
    if (lane < 32) hstart[((size_t)hh * NCHUNK + c) * 32 + i] = hv;
    float4 cur[4];
#pragma unroll
    for (int r = 0; r < 4; r++) cur[r] = pf0[r];
#pragma unroll
    for (int r = 0; r < 4; r++) pf0[r] = pf1[r];
#pragma unroll
    for (int r = 0; r < 4; r++) pf1[r] = pf2[r];
#pragma unroll
    for (int r = 0; r < 4; r++) pf2[r] = pf3[r];
    int cn = (c + 4 < NCHUNK) ? (c + 4) : (NCHUNK - 1);
#pragma unroll
    for (int r = 0; r < 4; r++)
      pf3[r] = ((const float4*)(row + (size_t)cn * cstride))[r];

    float a0 = 0.f, a1 = 0.f, a2 = 0.f, a3 = 0.f;
#pragma unroll
    for (int j4 = 0; j4 < 4; j4++) {
      float4 pv = cur[j4];
      a0 += pv.x * __shfl(hv, kb + j4 * 4 + 0);
      a1 += pv.y * __shfl(hv, kb + j4 * 4 + 1);
      a2 += pv.z * __shfl(hv, kb + j4 * 4 + 2);
      a3 += pv.w * __shfl(hv, kb + j4 * 4 + 3);
    }
    float y = (a0 + a1) + (a2 + a3);
    y += __shfl_xor(y, 32);
    float nn = y * y;
#pragma unroll
    for (int o = 16; o; o >>= 1) nn += __shfl_xor(nn, o);
    hv = y / (sqrtf(nn) + 1e-6f);
  }
}

// ---------------------------------------------------------------------------
// Phase 3 (per batch b): FULLY PARALLEL replay. h_t = normalize(M_t h_start).
// Shortcut: t==15, c<127 -> h_t bitwise-equals hstart[c+1].
// ---------------------------------------------------------------------------
__global__ __launch_bounds__(256) void mps_expand_par(
    const float* __restrict__ pref, const float* __restrict__ hstart,
    __bf16* __restrict__ ys, int tok0base) {
  int w = threadIdx.x >> 6, lane = threadIdx.x & 63;
  int i = lane & 31, half = lane >> 5;
  int task = blockIdx.x * 4 + w;          // [0, S_LEN*NH)
  int hh = task & 7, tok = task >> 3;
  int c = tok >> 4, t = tok & 15;
  int kb = half * 16;

  if (t == CHUNK - 1 && c < NCHUNK - 1) {   // wave-uniform branch
    if (lane < 32) {
      float hv2 = hstart[((size_t)hh * NCHUNK + c + 1) * 32 + i];
      ys[(size_t)(tok0base + tok) * (NH * DH) + hh * 32 + i] = (__bf16)hv2;
    }
    return;
  }

  float hv = hstart[((size_t)hh * NCHUNK + c) * 32 + i];
  const float4* Mr = (const float4*)(pref + (size_t)tok * NA
                     + (size_t)hh * (DH * DH) + i * 32 + half * 16);
  float4 m0 = Mr[0], m1 = Mr[1], m2 = Mr[2], m3 = Mr[3];

  float a0 = 0.f, a1 = 0.f, a2 = 0.f, a3 = 0.f;
  a0 += m0.x * __shfl(hv, kb + 0);  a1 += m0.y * __shfl(hv, kb + 1);
  a2 += m0.z * __shfl(hv, kb + 2);  a3 += m0.w * __shfl(hv, kb + 3);
  a0 += m1.x * __shfl(hv, kb + 4);  a1 += m1.y * __shfl(hv, kb + 5);
  a2 += m1.z * __shfl(hv, kb + 6);  a3 += m1.w * __shfl(hv, kb + 7);
  a0 += m2.x * __shfl(hv, kb + 8);  a1 += m2.y * __shfl(hv, kb + 9);
  a2 += m2.z * __shfl(hv, kb + 10); a3 += m2.w * __shfl(hv, kb + 11);
  a0 += m3.x * __shfl(hv, kb + 12); a1 += m3.y * __shfl(hv, kb + 13);
  a2 += m3.z * __shfl(hv, kb + 14); a3 += m3.w * __shfl(hv, kb + 15);
  float y = (a0 + a1) + (a2 + a3);
  y += __shfl_xor(y, 32);
  float nn = y * y;
#pragma unroll
  for (int o = 16; o; o >>= 1) nn += __shfl_xor(nn, o);
  float hvo = y / (sqrtf(nn) + 1e-6f);
  if (lane < 32)
    ys[(size_t)(tok0base + tok) * (NH * DH) + hh * 32 + i] = (__bf16)hvo;
}

// ---------------------------------------------------------------------------
extern "C" void kernel_launch(void* const* d_in, const int* in_sizes, int n_in,
                              void* d_out, int out_size, void* d_ws, size_t ws_size,
                              hipStream_t stream) {
  const float* x     = (const float*)d_in[0];
  const float* ln1_g = (const float*)d_in[1];
  const float* ln1_b = (const float*)d_in[2];
  const float* Wa    = (const float*)d_in[3];
  const float* ba    = (const float*)d_in[4];
  const float* h0    = (const float*)d_in[5];
  const float* Wo    = (const float*)d_in[6];
  const float* bo    = (const float*)d_in[7];
  const float* ln2_g = (const float*)d_in[8];
  const float* ln2_b = (const float*)d_in[9];
  const float* W1    = (const float*)d_in[10];
  const float* b1    = (const float*)d_in[11];
  const float* W2    = (const float*)d_in[12];
  const float* b2    = (const float*)d_in[13];
  float* out = (float*)d_out;

  char* wsb = (char*)d_ws;
  size_t off = 0;
  auto alloc = [&](size_t bytes) -> void* {
    void* p = wsb + off;
    off += (bytes + 255) & ~(size_t)255;
    return p;
  };
  __bf16* WoT   = (__bf16*)alloc((size_t)(NH * DH) * D_MODEL * 2);  // 0.5 MB
  __bf16* W1T   = (__bf16*)alloc((size_t)D_MODEL * D_FF * 2);       // 8 MB
  __bf16* W2T   = (__bf16*)alloc((size_t)D_FF * D_MODEL * 2);       // 8 MB
  __bf16* ys    = (__bf16*)alloc((size_t)NTOK * NH * DH * 2);       // 4 MB
  float*  hst   = (float*) alloc((size_t)NH * NCHUNK * DH * 4);     // 128 KB
  __bf16* xnh   = (__bf16*)alloc((size_t)NTOK * D_MODEL * 2);       // 16 MB
  __bf16* xnl   = (__bf16*)alloc((size_t)NTOK * D_MODEL * 2);       // 16 MB
  __bf16* WaTh  = (__bf16*)alloc((size_t)D_MODEL * NA * 2);         // 16 MB
  __bf16* WaTl  = (__bf16*)alloc((size_t)D_MODEL * NA * 2);         // 16 MB
  size_t tail0 = off;
  float*  Af32 = (float*) alloc((size_t)S_LEN * NA * 4);            // 64 MB
  __bf16* mid  = (__bf16*)(wsb + tail0);  // 64 MB, aliases Af32

  // 1) weights
  transpose_bf16<<<dim3(D_MODEL / 32, (NH * DH) / 32), 256, 0, stream>>>(Wo, WoT, NH * DH, D_MODEL);
  transpose_bf16<<<dim3(D_FF / 32, D_MODEL / 32), 256, 0, stream>>>(W1, W1T, D_MODEL, D_FF);
  transpose_bf16<<<dim3(D_MODEL / 32, D_FF / 32), 256, 0, stream>>>(W2, W2T, D_FF, D_MODEL);
  transpose_split<<<dim3(NA / 32, D_MODEL / 32), 256, 0, stream>>>(Wa, WaTh, WaTl, D_MODEL, NA);

  // 2) LN1 -> split hi/lo bf16
  ln_kernel<2><<<NTOK, 256, 0, stream>>>(x, ln1_g, ln1_b, xnh, xnl);

  // 3) per-batch: 8-phase virtual-K split A-GEMM + prefix recurrence
  for (int b = 0; b < BATCH; b++) {
    gemm8<1, 0, EPI_F32_BIAS_ONLY><<<dim3(NA / 256, S_LEN / 256), 512, 0, stream>>>(
        xnh + (size_t)b * S_LEN * D_MODEL, xnl + (size_t)b * S_LEN * D_MODEL,
        WaTh, WaTl, ba, Af32, S_LEN, NA, D_MODEL, D_MODEL);
    mps_chunkprod_f32<<<NH * NCHUNK, 64, 0, stream>>>(Af32);
    mps_chunkscan<<<NH, 64, 0, stream>>>(Af32, h0, hst);
    mps_expand_par<<<(S_LEN * NH) / 4, 256, 0, stream>>>(Af32, hst, ys, b * S_LEN);
  }

  // 4) x2 = x + ys @ Wo + bo   -> d_out (fp32)
  gemm_bf16<EPI_F32_BIAS_RES><<<dim3(D_MODEL / 128, NTOK / 128), 256, 0, stream>>>(
      ys, WoT, bo, x, out, NTOK, D_MODEL, NH * DH);

  // 5) LN2 -> bf16
  ln_kernel<0><<<NTOK, 256, 0, stream>>>(out, ln2_g, ln2_b, xnh, nullptr);

  // 6) mid = gelu(ln2 @ W1 + b1)  — 8-phase engine
  gemm8<0, 0, EPI_BF16_BIAS_GELU><<<dim3(D_FF / 256, NTOK / 256), 512, 0, stream>>>(
      xnh, nullptr, W1T, nullptr, b1, mid, NTOK, D_FF, D_MODEL, D_MODEL);

  // 7) out += mid @ W2 + b2  — split-K x2 on the gemm8 engine (grid z=2,
  //    256 blocks = 1/CU); out already holds x2; fp32 atomicAdd accumulate.
  gemm8<0, 1, EPI_F32_ATOMIC><<<dim3(D_MODEL / 256, NTOK / 256, 2), 512, 0, stream>>>(
      mid, nullptr, W2T, nullptr, b2, out, NTOK, D_MODEL, D_FF / 2, D_FF);
}

// Round 12
// 1283.571 us; speedup vs baseline: 1.0939x; 1.0939x over previous
//
#include <hip/hip_runtime.h>
#include <hip/hip_bf16.h>
#include <math.h>

typedef float f32x4 __attribute__((ext_vector_type(4)));
typedef __bf16 bf16x4 __attribute__((ext_vector_type(4)));
typedef __bf16 bf16x8 __attribute__((ext_vector_type(8)));

#define AS1(p) ((const __attribute__((address_space(1))) void*)(p))
#define AS3(p) ((__attribute__((address_space(3))) void*)(p))

static constexpr int D_MODEL = 1024;
static constexpr int S_LEN   = 2048;
static constexpr int BATCH   = 4;
static constexpr int NTOK    = BATCH * S_LEN;   // 8192
static constexpr int NH      = 8;
static constexpr int DH      = 32;
static constexpr int NA      = NH * DH * DH;    // 8192
static constexpr int D_FF    = 4096;
static constexpr int CHUNK   = 16;
static constexpr int NCHUNK  = S_LEN / CHUNK;   // 128

// GROUP_M=8 XCD-aware swizzle (requires gridDim.y % 8 == 0).
__device__ __forceinline__ void xcd_swizzle(int& bx, int& by) {
  int gx = gridDim.x;
  int orig = by * gx + bx;
  int r8 = orig & 7, j = orig >> 3;
  int bxn = j % gx, grp = j / gx;
  bx = bxn;
  by = grp * 8 + r8;
}

// Exact-GELU via A&S 7.1.26 erf approx (|eps| <= 1.5e-7 abs).
__device__ __forceinline__ float gelu_erf_fast(float v) {
  float z = fabsf(v) * 0.70710678118654752f;
  float t = __builtin_amdgcn_rcpf(fmaf(0.3275911f, z, 1.0f));
  float p = t * (0.254829592f + t * (-0.284496736f + t * (1.421413741f +
            t * (-1.453152027f + t * 1.061405429f))));
  float e = __builtin_amdgcn_exp2f(-1.4426950408889634f * z * z);
  float er = 1.0f - p * e;
  er = (v < 0.0f) ? -er : er;
  return 0.5f * v * (1.0f + er);
}

// ---------------------------------------------------------------------------
// Transpose fp32 [R][C] -> bf16 [C][R]
// ---------------------------------------------------------------------------
__global__ __launch_bounds__(256) void transpose_bf16(
    const float* __restrict__ in, __bf16* __restrict__ out, int R, int C) {
  __shared__ float tile[32][33];
  int tx = threadIdx.x & 31, ty = threadIdx.x >> 5;   // 32 x 8
  int c0 = blockIdx.x * 32, r0 = blockIdx.y * 32;
  for (int i = ty; i < 32; i += 8)
    tile[i][tx] = in[(size_t)(r0 + i) * C + c0 + tx];
  __syncthreads();
  for (int i = ty; i < 32; i += 8)
    out[(size_t)(c0 + i) * R + r0 + tx] = (__bf16)tile[tx][i];
}

// ---------------------------------------------------------------------------
// Transpose fp32 [R][C] -> SPLIT bf16 hi/lo [C][R]  (x = hi + lo)
// ---------------------------------------------------------------------------
__global__ __launch_bounds__(256) void transpose_split(
    const float* __restrict__ in, __bf16* __restrict__ ohi,
    __bf16* __restrict__ olo, int R, int C) {
  __shared__ float tile[32][33];
  int tx = threadIdx.x & 31, ty = threadIdx.x >> 5;
  int c0 = blockIdx.x * 32, r0 = blockIdx.y * 32;
  for (int i = ty; i < 32; i += 8)
    tile[i][tx] = in[(size_t)(r0 + i) * C + c0 + tx];
  __syncthreads();
  for (int i = ty; i < 32; i += 8) {
    float v = tile[tx][i];
    __bf16 h = (__bf16)v;
    ohi[(size_t)(c0 + i) * R + r0 + tx] = h;
    olo[(size_t)(c0 + i) * R + r0 + tx] = (__bf16)(v - (float)h);
  }
}

// ---------------------------------------------------------------------------
// LayerNorm: fp32 in. MODE=1 -> fp32; =0 -> bf16; =2 -> split hi/lo bf16
// ---------------------------------------------------------------------------
template <int MODE>
__global__ __launch_bounds__(256) void ln_kernel(
    const float* __restrict__ in, const float* __restrict__ g,
    const float* __restrict__ bta, void* __restrict__ outv,
    void* __restrict__ outv2) {
  int row = blockIdx.x, tid = threadIdx.x;
  const float4* in4 = (const float4*)(in + (size_t)row * D_MODEL);
  float4 v = in4[tid];
  float s  = v.x + v.y + v.z + v.w;
  float ss = v.x * v.x + v.y * v.y + v.z * v.z + v.w * v.w;
  for (int o = 32; o; o >>= 1) { s += __shfl_down(s, o); ss += __shfl_down(ss, o); }
  __shared__ float ps[4], pq[4];
  int lane = tid & 63, w = tid >> 6;
  if (lane == 0) { ps[w] = s; pq[w] = ss; }
  __syncthreads();
  s  = ps[0] + ps[1] + ps[2] + ps[3];
  ss = pq[0] + pq[1] + pq[2] + pq[3];
  float mean = s * (1.0f / D_MODEL);
  float var  = ss * (1.0f / D_MODEL) - mean * mean;
  float inv  = rsqrtf(fmaxf(var, 0.0f) + 1e-5f);
  float4 gv = ((const float4*)g)[tid];
  float4 bv = ((const float4*)bta)[tid];
  float o0 = (v.x - mean) * inv * gv.x + bv.x;
  float o1 = (v.y - mean) * inv * gv.y + bv.y;
  float o2 = (v.z - mean) * inv * gv.z + bv.z;
  float o3 = (v.w - mean) * inv * gv.w + bv.w;
  if (MODE == 1) {
    float4 o = {o0, o1, o2, o3};
    ((float4*)outv)[(size_t)row * (D_MODEL / 4) + tid] = o;
  } else if (MODE == 0) {
    bf16x4 o;
    o[0] = (__bf16)o0; o[1] = (__bf16)o1; o[2] = (__bf16)o2; o[3] = (__bf16)o3;
    ((bf16x4*)outv)[(size_t)row * (D_MODEL / 4) + tid] = o;
  } else {
    bf16x4 oh, ol;
    oh[0] = (__bf16)o0; oh[1] = (__bf16)o1; oh[2] = (__bf16)o2; oh[3] = (__bf16)o3;
    ol[0] = (__bf16)(o0 - (float)oh[0]);
    ol[1] = (__bf16)(o1 - (float)oh[1]);
    ol[2] = (__bf16)(o2 - (float)oh[2]);
    ol[3] = (__bf16)(o3 - (float)oh[3]);
    ((bf16x4*)outv )[(size_t)row * (D_MODEL / 4) + tid] = oh;
    ((bf16x4*)outv2)[(size_t)row * (D_MODEL / 4) + tid] = ol;
  }
}

enum { EPI_BF16_BIAS = 0, EPI_BF16_BIAS_GELU = 1, EPI_F32_BIAS_RES = 2,
       EPI_F32_BIAS_ONLY = 3, EPI_F32_ATOMIC = 4 };

#define SB0() __builtin_amdgcn_sched_barrier(0)
#define BARRIER()                                      \
  do {                                                 \
    SB0();                                             \
    __builtin_amdgcn_s_barrier();                      \
    SB0();                                             \
  } while (0)
#define LGKM0()                                        \
  do {                                                 \
    asm volatile("s_waitcnt lgkmcnt(0)" ::: "memory"); \
    SB0();                                             \
  } while (0)
#define GEMM8_QUAD(I0, J0)                                                   \
  do {                                                                       \
    __builtin_amdgcn_s_setprio(1);                                           \
    _Pragma("unroll") for (int i_ = 0; i_ < 4; ++i_)                         \
    _Pragma("unroll") for (int j_ = 0; j_ < 2; ++j_)                         \
    _Pragma("unroll") for (int k_ = 0; k_ < 2; ++k_)                         \
      acc[(I0) + i_][(J0) + j_] = __builtin_amdgcn_mfma_f32_16x16x32_bf16(   \
          a[(I0) + i_][k_], b[(J0) + j_][k_], acc[(I0) + i_][(J0) + j_],     \
          0, 0, 0);                                                          \
    __builtin_amdgcn_s_setprio(0);                                           \
  } while (0)

// ---------------------------------------------------------------------------
// 8-wave 256x256 MFMA GEMM, software-pipelined phases (bench-verified r6-r11).
// SPLIT=1: virtual K=3072 over (Ahi*Bhi + Ahi*Blo + Alo*Bhi), Kstride=1024.
// SPLITK=1: gridDim.z K-parts; EPI_F32_ATOMIC accumulates into out (which
//   pre-holds the residual base); b2 folded into z==0's bias.
// ---------------------------------------------------------------------------
template <int SPLIT, int SPLITK, int EPI>
__global__ __launch_bounds__(512, 2) void gemm8(
    const __bf16* __restrict__ pA, const __bf16* __restrict__ pA2,
    const __bf16* __restrict__ pB, const __bf16* __restrict__ pB2,
    const float* __restrict__ bias, void* __restrict__ out,
    int M, int N, int K, int kstride) {
  __shared__ alignas(16) char lds[131072];   // A: [0,64K) 2 bufs; B: [64K,128K)
  const int tid = threadIdx.x;
  const int lane = tid & 63, w = tid >> 6;
  const int fm = lane & 15, fq = lane >> 4;
  const int wm2 = w >> 2, wn4 = w & 3;
  int bx = blockIdx.x, by = blockIdx.y;
  xcd_swizzle(bx, by);
  const int m0 = by * 256, n0 = bx * 256;
  const int NT = SPLIT ? 48 : (K >> 6);
  const int KS = SPLIT ? D_MODEL : kstride;

  const size_t kzoff = SPLITK ? (size_t)blockIdx.z * (size_t)K : 0;
  const __bf16* pAz = pA + kzoff;
  const __bf16* pBz = pB + kzoff;

  const int lrow8 = lane >> 3;
  const int lslot = ((lane & 7) ^ lrow8) << 3;

  auto stageA = [&](int kt, int h) {
    const __bf16* base = SPLIT ? ((kt < 32) ? pA : pA2) : pAz;
    int kc = SPLIT ? ((kt & 15) << 6) : (kt << 6);
    char* d0 = lds + ((kt & 1) << 15);
#pragma unroll
    for (int j = 0; j < 2; ++j) {
      int rb = h * 128 + j * 64 + w * 8;
      const __bf16* src = base + (size_t)(m0 + rb + lrow8) * KS + kc + lslot;
      __builtin_amdgcn_global_load_lds(AS1(src), AS3(d0 + rb * 128 + lane * 16), 16, 0, 0);
    }
  };
  auto stageB = [&](int kt, int h) {
    const __bf16* base = SPLIT ? ((kt >= 16 && kt < 32) ? pB2 : pB) : pBz;
    int kc = SPLIT ? ((kt & 15) << 6) : (kt << 6);
    char* d0 = lds + 65536 + ((kt & 1) << 15);
#pragma unroll
    for (int j = 0; j < 2; ++j) {
      int rb = h * 128 + j * 64 + w * 8;
      const __bf16* src = base + (size_t)(n0 + rb + lrow8) * KS + kc + lslot;
      __builtin_amdgcn_global_load_lds(AS1(src), AS3(d0 + rb * 128 + lane * 16), 16, 0, 0);
    }
  };
  auto rdA = [&](int bo, int i, int ks) -> bf16x8 {
    int row = wm2 * 128 + i * 16 + fm;
    return *(const bf16x8*)(lds + bo + row * 128 +
                            ((((ks << 2) + fq) ^ (row & 7)) << 4));
  };
  auto rdB = [&](int bo, int j, int ks) -> bf16x8 {
    int row = wn4 * 64 + j * 16 + fm;
    return *(const bf16x8*)(lds + 65536 + bo + row * 128 +
                            ((((ks << 2) + fq) ^ (row & 7)) << 4));
  };

  f32x4 acc[8][4];
#pragma unroll
  for (int i = 0; i < 8; ++i)
#pragma unroll
    for (int j = 0; j < 4; ++j)
#pragma unroll
      for (int r = 0; r < 4; ++r) acc[i][j][r] = 0.0f;

  stageA(0, 0); stageA(0, 1); stageB(0, 0); stageB(0, 1);
  if (NT > 1) stageA(1, 0);
  SB0();
  if (NT > 1) asm volatile("s_waitcnt vmcnt(2)" ::: "memory");
  else        asm volatile("s_waitcnt vmcnt(0)" ::: "memory");
  BARRIER();
  bf16x8 a[8][2], b[4][2];
#pragma unroll
  for (int i = 0; i < 4; ++i) { a[i][0] = rdA(0, i, 0); a[i][1] = rdA(0, i, 1); }
#pragma unroll
  for (int j = 0; j < 2; ++j) { b[j][0] = rdB(0, j, 0); b[j][1] = rdB(0, j, 1); }

  for (int t = 0; t < NT; ++t) {
    const int bo  = (t & 1) << 15;
    const int bon = ((t + 1) & 1) << 15;
    // ---- ph0
    BARRIER();
    if (t + 1 < NT) { stageA(t + 1, 1); stageB(t + 1, 0); }
    LGKM0();
#pragma unroll
    for (int j = 2; j < 4; ++j) { b[j][0] = rdB(bo, j, 0); b[j][1] = rdB(bo, j, 1); }
    SB0();
    GEMM8_QUAD(0, 0);
    // ---- ph1
    BARRIER();
    if (t + 1 < NT) stageB(t + 1, 1);
    LGKM0();
#pragma unroll
    for (int i = 4; i < 8; ++i) { a[i][0] = rdA(bo, i, 0); a[i][1] = rdA(bo, i, 1); }
    SB0();
    GEMM8_QUAD(0, 2);
    // ---- ph2
    BARRIER();
    LGKM0();
    GEMM8_QUAD(4, 0);
    // ---- ph3
    BARRIER();
    if (t + 2 < NT) stageA(t + 2, 0);
    SB0();
    if (t + 1 < NT) {
      if (t + 2 < NT) asm volatile("s_waitcnt vmcnt(2)" ::: "memory");
      else            asm volatile("s_waitcnt vmcnt(0)" ::: "memory");
      BARRIER();
#pragma unroll
      for (int i = 0; i < 4; ++i) { a[i][0] = rdA(bon, i, 0); a[i][1] = rdA(bon, i, 1); }
#pragma unroll
      for (int j = 0; j < 2; ++j) { b[j][0] = rdB(bon, j, 0); b[j][1] = rdB(bon, j, 1); }
      SB0();
    }
    GEMM8_QUAD(4, 2);
  }
  __syncthreads();

  if (EPI == EPI_F32_BIAS_ONLY) {
    float* outF = (float*)out;
#pragma unroll
    for (int j = 0; j < 4; ++j) {
      int col = n0 + wn4 * 64 + j * 16 + fm;
      float bv = bias[col];
#pragma unroll
      for (int i = 0; i < 8; ++i)
#pragma unroll
        for (int r = 0; r < 4; ++r) {
          int row = m0 + wm2 * 128 + i * 16 + fq * 4 + r;
          outF[(size_t)row * N + col] = acc[i][j][r] + bv;
        }
    }
  } else if (EPI == EPI_F32_ATOMIC) {
    float* outF = (float*)out;
#pragma unroll
    for (int j = 0; j < 4; ++j) {
      int col = n0 + wn4 * 64 + j * 16 + fm;
      float bv = (blockIdx.z == 0) ? bias[col] : 0.0f;
#pragma unroll
      for (int i = 0; i < 8; ++i)
#pragma unroll
        for (int r = 0; r < 4; ++r) {
          int row = m0 + wm2 * 128 + i * 16 + fq * 4 + r;
          atomicAdd(&outF[(size_t)row * N + col], acc[i][j][r] + bv);
        }
    }
  } else {  // EPI_BF16_BIAS_GELU
    char* patch = lds + w * 16384;
    float bv4[4];
#pragma unroll
    for (int j = 0; j < 4; ++j) bv4[j] = bias[n0 + wn4 * 64 + j * 16 + fm];
#pragma unroll
    for (int i = 0; i < 8; ++i)
#pragma unroll
      for (int j = 0; j < 4; ++j)
#pragma unroll
        for (int r = 0; r < 4; ++r) {
          float v = gelu_erf_fast(acc[i][j][r] + bv4[j]);
          *(__bf16*)(patch + (i * 16 + fq * 4 + r) * 128 + (j * 16 + fm) * 2) =
              (__bf16)v;
        }
    asm volatile("s_waitcnt lgkmcnt(0)" ::: "memory");
#pragma unroll
    for (int rr = 0; rr < 16; ++rr) {
      bf16x8 ov = *(const bf16x8*)(patch + (rr * 8 + lrow8) * 128 + (lane & 7) * 16);
      size_t grow = (size_t)(m0 + wm2 * 128 + rr * 8 + lrow8);
      *(bf16x8*)((__bf16*)out + grow * N + n0 + wn4 * 64 + (lane & 7) * 8) = ov;
    }
  }
}

// ---------------------------------------------------------------------------
// bf16 MFMA GEMM, m97 structure + GROUP_M=8 XCD swizzle (step 4).
// Plain (256) bounds — the (256,3) variant regressed ~15us in r11.
// ---------------------------------------------------------------------------
template <int EPI>
__global__ __launch_bounds__(256) void gemm_bf16(
    const __bf16* __restrict__ Amat, const __bf16* __restrict__ BT,
    const float* __restrict__ bias, const float* __restrict__ res,
    void* __restrict__ out, int M, int N, int K) {
  __shared__ __bf16 smem[2 * 128 * 32];        // As | Bs (contiguous 16KB)
  __bf16* As = smem;
  __bf16* Bs = smem + 128 * 32;
  const int tid = threadIdx.x;
  const int lane = tid & 63, w = tid >> 6;
  int bx = blockIdx.x, by = blockIdx.y;
  xcd_swizzle(bx, by);
  const int m0 = by * 128, n0 = bx * 128;
  const int wm = (w >> 1) * 64, wn = (w & 1) * 64;

  f32x4 acc[4][4];
#pragma unroll
  for (int a = 0; a < 4; a++)
#pragma unroll
    for (int b = 0; b < 4; b++)
#pragma unroll
      for (int r = 0; r < 4; r++) acc[a][b][r] = 0.0f;

  const int srow = tid >> 2;
  const int soff = (tid & 3) * 16;
  const __bf16* gA0 = Amat + (size_t)(m0 + srow) * K + (soff >> 1);
  const __bf16* gA1 = Amat + (size_t)(m0 + srow + 64) * K + (soff >> 1);
  const __bf16* gB0 = BT + (size_t)(n0 + srow) * K + (soff >> 1);
  const __bf16* gB1 = BT + (size_t)(n0 + srow + 64) * K + (soff >> 1);
  char* lA0 = (char*)As + srow * 64 + soff;
  char* lA1 = (char*)As + (srow + 64) * 64 + soff;
  char* lB0 = (char*)Bs + srow * 64 + soff;
  char* lB1 = (char*)Bs + (srow + 64) * 64 + soff;

  const int fm = lane & 15, fq = lane >> 4;
  for (int k0 = 0; k0 < K; k0 += 32) {
    __builtin_amdgcn_global_load_lds(AS1(gA0 + k0), AS3(lA0), 16, 0, 0);
    __builtin_amdgcn_global_load_lds(AS1(gA1 + k0), AS3(lA1), 16, 0, 0);
    __builtin_amdgcn_global_load_lds(AS1(gB0 + k0), AS3(lB0), 16, 0, 0);
    __builtin_amdgcn_global_load_lds(AS1(gB1 + k0), AS3(lB1), 16, 0, 0);
    __syncthreads();
    bf16x8 af[4], bf[4];
#pragma unroll
    for (int t = 0; t < 4; t++)
      af[t] = *(const bf16x8*)((const char*)As + (wm + t * 16 + fm) * 64 + fq * 16);
#pragma unroll
    for (int t = 0; t < 4; t++)
      bf[t] = *(const bf16x8*)((const char*)Bs + (wn + t * 16 + fm) * 64 + fq * 16);
#pragma unroll
    for (int tm = 0; tm < 4; tm++)
#pragma unroll
      for (int tn = 0; tn < 4; tn++)
        acc[tm][tn] = __builtin_amdgcn_mfma_f32_16x16x32_bf16(af[tm], bf[tn], acc[tm][tn], 0, 0, 0);
    __syncthreads();
  }

#pragma unroll
  for (int tn = 0; tn < 4; tn++) {
    int col = n0 + wn + tn * 16 + fm;
    float bv = bias[col];
#pragma unroll
    for (int tm = 0; tm < 4; tm++) {
#pragma unroll
      for (int r = 0; r < 4; r++) {
        int row = m0 + wm + tm * 16 + fq * 4 + r;
        float v = acc[tm][tn][r] + bv;
        size_t idx = (size_t)row * N + col;
        if (EPI == EPI_F32_BIAS_RES) {
          ((float*)out)[idx] = v + res[idx];
        } else if (EPI == EPI_BF16_BIAS_GELU) {
          v = gelu_erf_fast(v);
          ((__bf16*)out)[idx] = (__bf16)v;
        } else {
          ((__bf16*)out)[idx] = (__bf16)v;
        }
      }
    }
  }
}

// ---------------------------------------------------------------------------
// Phase 1 (per batch b): prefix products, IN PLACE over A — 4-WAVE version.
// 256 thr/block, task = (hh,c). Lane (wid, rh, jj) computes 4 output rows
// (rbase=wid*8+rh*4) of column jj. cur lives in LDS [k][jj] (column read =
// 32 conflict-free b32; 2-way-free writes); A-row reads are 2-way broadcast
// b128. Accumulation order IDENTICAL to the 1-wave version (a0..a3 by k%4,
// pairwise sum) -> bitwise-same prefixes; scan/expand untouched.
// 1024 blocks x 4 waves = 4 waves/SIMD (was 1) — latency finally hidden.
// ---------------------------------------------------------------------------
__global__ __launch_bounds__(256) void mps_chunkprod_f32(
    float* __restrict__ A) {
  int bid = blockIdx.x;            // hh*128 + c
  int c = bid & 127, hh = bid >> 7;
  int tid = threadIdx.x;
  int wid = tid >> 6, lane = tid & 63;
  int jj = lane & 31, rh = lane >> 5;
  int rbase = wid * 8 + rh * 4;    // 4 rows per lane

  __shared__ float curs[DH * DH];       // cur [k][jj], 4 KB
  __shared__ float Albuf[2][DH * DH];   // staged A_t, 2 x 4 KB

  // cur = I
#pragma unroll
  for (int r = 0; r < 4; r++)
    curs[(rbase + r) * 32 + jj] = (rbase + r == jj) ? 1.0f : 0.0f;

  float* Abase = A + (size_t)(c * CHUNK) * NA + (size_t)hh * (DH * DH);

  ((float4*)Albuf[0])[tid] = ((const float4*)Abase)[tid];   // stage t=0 (4KB)
  __syncthreads();

  for (int t = 0; t < CHUNK; t++) {
    int cb = t & 1;
    float4 pf;
    if (t + 1 < CHUNK)   // reg prefetch of next A tile (vmcnt hidden by compute)
      pf = ((const float4*)(Abase + (size_t)(t + 1) * NA))[tid];

    // read own cur column (32 x b32, conflict-free: distinct banks per jj)
    float cc[32];
#pragma unroll
    for (int k = 0; k < 32; k++) cc[k] = curs[k * 32 + jj];

    float nx[4];
#pragma unroll
    for (int r = 0; r < 4; r++) {
      const float4* ap = (const float4*)&Albuf[cb][(rbase + r) * 32];
      float a0 = 0.f, a1 = 0.f, a2 = 0.f, a3 = 0.f;
#pragma unroll
      for (int k4 = 0; k4 < 8; k4++) {
        float4 av = ap[k4];
        a0 += av.x * cc[k4 * 4 + 0];
        a1 += av.y * cc[k4 * 4 + 1];
        a2 += av.z * cc[k4 * 4 + 2];
        a3 += av.w * cc[k4 * 4 + 3];
      }
      nx[r] = (a0 + a1) + (a2 + a3);
    }

    // store prefix M_t over slot t (coalesced 128B row segments)
    {
      float* slot = Abase + (size_t)t * NA;
#pragma unroll
      for (int r = 0; r < 4; r++)
        slot[(rbase + r) * 32 + jj] = nx[r];
    }

    __syncthreads();   // all cur reads done before overwrite
#pragma unroll
    for (int r = 0; r < 4; r++)
      curs[(rbase + r) * 32 + jj] = nx[r];
    if (t + 1 < CHUNK)
      ((float4*)Albuf[cb ^ 1])[tid] = pf;
    __syncthreads();   // cur + next A visible
  }
}

// ---------------------------------------------------------------------------
// Phase 2 (per batch b): sequential scan over chunk products per head.
// Depth-4 register prefetch (named regs, static indices).
// ---------------------------------------------------------------------------
__global__ __launch_bounds__(64) void mps_chunkscan(
    const float* __restrict__ pref, const float* __restrict__ h0,
    float* __restrict__ hstart) {
  int hh = blockIdx.x;
  int lane = threadIdx.x, i = lane & 31, half = lane >> 5;
  float hv = h0[hh * 32 + i];
  const size_t cstride = (size_t)CHUNK * NA;
  const float* row = pref + (size_t)(CHUNK - 1) * NA + (size_t)hh * (DH * DH)
                     + i * 32 + half * 16;
  int kb = half * 16;

  float4 pf0[4], pf1[4], pf2[4], pf3[4];
#pragma unroll
  for (int r = 0; r < 4; r++) pf0[r] = ((const float4*)row)[r];
#pragma unroll
  for (int r = 0; r < 4; r++) pf1[r] = ((const float4*)(row + cstride))[r];
#pragma unroll
  for (int r = 0; r < 4; r++) pf2[r] = ((const float4*)(row + 2 * cstride))[r];
#pragma unroll
  for (int r = 0; r < 4; r++) pf3[r] = ((const float4*)(row + 3 * cstride))[r];

  for (int c = 0; c < NCHUNK; c++) {
    if (lane < 32) hstart[((size_t)hh * NCHUNK + c) * 32 + i] = hv;
    float4 cur[4];
#pragma unroll
    for (int r = 0; r < 4; r++) cur[r] = pf0[r];
#pragma unroll
    for (int r = 0; r < 4; r++) pf0[r] = pf1[r];
#pragma unroll
    for (int r = 0; r < 4; r++) pf1[r] = pf2[r];
#pragma unroll
    for (int r = 0; r < 4; r++) pf2[r] = pf3[r];
    int cn = (c + 4 < NCHUNK) ? (c + 4) : (NCHUNK - 1);
#pragma unroll
    for (int r = 0; r < 4; r++)
      pf3[r] = ((const float4*)(row + (size_t)cn * cstride))[r];

    float a0 = 0.f, a1 = 0.f, a2 = 0.f, a3 = 0.f;
#pragma unroll
    for (int j4 = 0; j4 < 4; j4++) {
      float4 pv = cur[j4];
      a0 += pv.x * __shfl(hv, kb + j4 * 4 + 0);
      a1 += pv.y * __shfl(hv, kb + j4 * 4 + 1);
      a2 += pv.z * __shfl(hv, kb + j4 * 4 + 2);
      a3 += pv.w * __shfl(hv, kb + j4 * 4 + 3);
    }
    float y = (a0 + a1) + (a2 + a3);
    y += __shfl_xor(y, 32);
    float nn = y * y;
#pragma unroll
    for (int o = 16; o; o >>= 1) nn += __shfl_xor(nn, o);
    hv = y / (sqrtf(nn) + 1e-6f);
  }
}

// ---------------------------------------------------------------------------
// Phase 3 (per batch b): FULLY PARALLEL replay. h_t = normalize(M_t h_start).
// Shortcut: t==15, c<127 -> h_t bitwise-equals hstart[c+1].
// ---------------------------------------------------------------------------
__global__ __launch_bounds__(256) void mps_expand_par(
    const float* __restrict__ pref, const float* __restrict__ hstart,
    __bf16* __restrict__ ys, int tok0base) {
  int w = threadIdx.x >> 6, lane = threadIdx.x & 63;
  int i = lane & 31, half = lane >> 5;
  int task = blockIdx.x * 4 + w;          // [0, S_LEN*NH)
  int hh = task & 7, tok = task >> 3;
  int c = tok >> 4, t = tok & 15;
  int kb = half * 16;

  if (t == CHUNK - 1 && c < NCHUNK - 1) {   // wave-uniform branch
    if (lane < 32) {
      float hv2 = hstart[((size_t)hh * NCHUNK + c + 1) * 32 + i];
      ys[(size_t)(tok0base + tok) * (NH * DH) + hh * 32 + i] = (__bf16)hv2;
    }
    return;
  }

  float hv = hstart[((size_t)hh * NCHUNK + c) * 32 + i];
  const float4* Mr = (const float4*)(pref + (size_t)tok * NA
                     + (size_t)hh * (DH * DH) + i * 32 + half * 16);
  float4 m0 = Mr[0], m1 = Mr[1], m2 = Mr[2], m3 = Mr[3];

  float a0 = 0.f, a1 = 0.f, a2 = 0.f, a3 = 0.f;
  a0 += m0.x * __shfl(hv, kb + 0);  a1 += m0.y * __shfl(hv, kb + 1);
  a2 += m0.z * __shfl(hv, kb + 2);  a3 += m0.w * __shfl(hv, kb + 3);
  a0 += m1.x * __shfl(hv, kb + 4);  a1 += m1.y * __shfl(hv, kb + 5);
  a2 += m1.z * __shfl(hv, kb + 6);  a3 += m1.w * __shfl(hv, kb + 7);
  a0 += m2.x * __shfl(hv, kb + 8);  a1 += m2.y * __shfl(hv, kb + 9);
  a2 += m2.z * __shfl(hv, kb + 10); a3 += m2.w * __shfl(hv, kb + 11);
  a0 += m3.x * __shfl(hv, kb + 12); a1 += m3.y * __shfl(hv, kb + 13);
  a2 += m3.z * __shfl(hv, kb + 14); a3 += m3.w * __shfl(hv, kb + 15);
  float y = (a0 + a1) + (a2 + a3);
  y += __shfl_xor(y, 32);
  float nn = y * y;
#pragma unroll
  for (int o = 16; o; o >>= 1) nn += __shfl_xor(nn, o);
  float hvo = y / (sqrtf(nn) + 1e-6f);
  if (lane < 32)
    ys[(size_t)(tok0base + tok) * (NH * DH) + hh * 32 + i] = (__bf16)hvo;
}

// ---------------------------------------------------------------------------
extern "C" void kernel_launch(void* const* d_in, const int* in_sizes, int n_in,
                              void* d_out, int out_size, void* d_ws, size_t ws_size,
                              hipStream_t stream) {
  const float* x     = (const float*)d_in[0];
  const float* ln1_g = (const float*)d_in[1];
  const float* ln1_b = (const float*)d_in[2];
  const float* Wa    = (const float*)d_in[3];
  const float* ba    = (const float*)d_in[4];
  const float* h0    = (const float*)d_in[5];
  const float* Wo    = (const float*)d_in[6];
  const float* bo    = (const float*)d_in[7];
  const float* ln2_g = (const float*)d_in[8];
  const float* ln2_b = (const float*)d_in[9];
  const float* W1    = (const float*)d_in[10];
  const float* b1    = (const float*)d_in[11];
  const float* W2    = (const float*)d_in[12];
  const float* b2    = (const float*)d_in[13];
  float* out = (float*)d_out;

  char* wsb = (char*)d_ws;
  size_t off = 0;
  auto alloc = [&](size_t bytes) -> void* {
    void* p = wsb + off;
    off += (bytes + 255) & ~(size_t)255;
    return p;
  };
  __bf16* WoT   = (__bf16*)alloc((size_t)(NH * DH) * D_MODEL * 2);  // 0.5 MB
  __bf16* W1T   = (__bf16*)alloc((size_t)D_MODEL * D_FF * 2);       // 8 MB
  __bf16* W2T   = (__bf16*)alloc((size_t)D_FF * D_MODEL * 2);       // 8 MB
  __bf16* ys    = (__bf16*)alloc((size_t)NTOK * NH * DH * 2);       // 4 MB
  float*  hst   = (float*) alloc((size_t)NH * NCHUNK * DH * 4);     // 128 KB
  __bf16* xnh   = (__bf16*)alloc((size_t)NTOK * D_MODEL * 2);       // 16 MB
  __bf16* xnl   = (__bf16*)alloc((size_t)NTOK * D_MODEL * 2);       // 16 MB
  __bf16* WaTh  = (__bf16*)alloc((size_t)D_MODEL * NA * 2);         // 16 MB
  __bf16* WaTl  = (__bf16*)alloc((size_t)D_MODEL * NA * 2);         // 16 MB
  size_t tail0 = off;
  float*  Af32 = (float*) alloc((size_t)S_LEN * NA * 4);            // 64 MB
  __bf16* mid  = (__bf16*)(wsb + tail0);  // 64 MB, aliases Af32

  // 1) weights
  transpose_bf16<<<dim3(D_MODEL / 32, (NH * DH) / 32), 256, 0, stream>>>(Wo, WoT, NH * DH, D_MODEL);
  transpose_bf16<<<dim3(D_FF / 32, D_MODEL / 32), 256, 0, stream>>>(W1, W1T, D_MODEL, D_FF);
  transpose_bf16<<<dim3(D_MODEL / 32, D_FF / 32), 256, 0, stream>>>(W2, W2T, D_FF, D_MODEL);
  transpose_split<<<dim3(NA / 32, D_MODEL / 32), 256, 0, stream>>>(Wa, WaTh, WaTl, D_MODEL, NA);

  // 2) LN1 -> split hi/lo bf16
  ln_kernel<2><<<NTOK, 256, 0, stream>>>(x, ln1_g, ln1_b, xnh, xnl);

  // 3) per-batch: 8-phase virtual-K split A-GEMM + prefix recurrence
  for (int b = 0; b < BATCH; b++) {
    gemm8<1, 0, EPI_F32_BIAS_ONLY><<<dim3(NA / 256, S_LEN / 256), 512, 0, stream>>>(
        xnh + (size_t)b * S_LEN * D_MODEL, xnl + (size_t)b * S_LEN * D_MODEL,
        WaTh, WaTl, ba, Af32, S_LEN, NA, D_MODEL, D_MODEL);
    mps_chunkprod_f32<<<NH * NCHUNK, 256, 0, stream>>>(Af32);
    mps_chunkscan<<<NH, 64, 0, stream>>>(Af32, h0, hst);
    mps_expand_par<<<(S_LEN * NH) / 4, 256, 0, stream>>>(Af32, hst, ys, b * S_LEN);
  }

  // 4) x2 = x + ys @ Wo + bo   -> d_out (fp32)
  gemm_bf16<EPI_F32_BIAS_RES><<<dim3(D_MODEL / 128, NTOK / 128), 256, 0, stream>>>(
      ys, WoT, bo, x, out, NTOK, D_MODEL, NH * DH);

  // 5) LN2 -> bf16
  ln_kernel<0><<<NTOK, 256, 0, stream>>>(out, ln2_g, ln2_b, xnh, nullptr);

  // 6) mid = gelu(ln2 @ W1 + b1)  — 8-phase engine
  gemm8<0, 0, EPI_BF16_BIAS_GELU><<<dim3(D_FF / 256, NTOK / 256), 512, 0, stream>>>(
      xnh, nullptr, W1T, nullptr, b1, mid, NTOK, D_FF, D_MODEL, D_MODEL);

  // 7) out += mid @ W2 + b2  — split-K x2 on the gemm8 engine
  gemm8<0, 1, EPI_F32_ATOMIC><<<dim3(D_MODEL / 256, NTOK / 256, 2), 512, 0, stream>>>(
      mid, nullptr, W2T, nullptr, b2, out, NTOK, D_MODEL, D_FF / 2, D_FF);
}